// Round 5
// baseline (249.830 us; speedup 1.0000x reference)
//
#include <hip/hip_runtime.h>

// GradeWiseLinear: x (8,2048,128,16) f32, block-diagonal linear over last dim,
// grade dims {1,4,6,4,1}. Memory-bound: 268 MB traffic, copy-roofline ~43 us.
//
// R5: persistent grid-stride kernel (1024 blocks, 8 tiles each) with a 2-deep
// software pipeline: next tile's 4 coalesced dwordx4 loads issue before the
// current tile's compute+store, so loads stay in flight across tiles and the
// LDS-stage/syncthreads/kernarg startup is paid once per block, not per tile.
// Neighbor elements via intra-wave shuffles; nontemporal stores.

typedef float v4f __attribute__((ext_vector_type(4)));

__global__ __launch_bounds__(256) void GradeWiseLinear_kernel(
    const float* __restrict__ x,
    const float* __restrict__ w0, const float* __restrict__ b0,
    const float* __restrict__ w1, const float* __restrict__ b1,
    const float* __restrict__ w2, const float* __restrict__ b2,
    const float* __restrict__ w3, const float* __restrict__ b3,
    const float* __restrict__ w4, const float* __restrict__ b4,
    float* __restrict__ out, int n_tiles)
{
    // Packed LDS weights/biases (wave-uniform broadcast reads, conflict-free):
    // [0] w0 | [1..16] w1 | [17..52] w2 | [53..68] w3 | [69] w4 | [70..85] biases
    __shared__ float s[86];
    {
        int t = threadIdx.x;
        if (t < 86) {
            float v;
            if      (t == 0)  v = w0[0];
            else if (t < 17)  v = w1[t - 1];
            else if (t < 53)  v = w2[t - 17];
            else if (t < 69)  v = w3[t - 53];
            else if (t == 69) v = w4[0];
            else if (t == 70) v = b0[0];
            else if (t < 75)  v = b1[t - 71];
            else if (t < 81)  v = b2[t - 75];
            else if (t < 85)  v = b3[t - 81];
            else              v = b4[0];
            s[t] = v;
        }
    }
    __syncthreads();

    const int t = threadIdx.x;
    const int j = t & 3;                 // chunk-in-row role, fixed per thread
    const v4f* xv = (const v4f*)x;
    v4f* ov = (v4f*)out;

    int tt = blockIdx.x;
    int base = tt * 1024 + t;

    v4f cur[4];
    #pragma unroll
    for (int k = 0; k < 4; ++k) cur[k] = xv[base + 256 * k];

    while (true) {
        // ---- prefetch next tile (stays in flight across compute) ----
        const int tt_n = tt + (int)gridDim.x;
        const bool have_next = tt_n < n_tiles;
        const int base_n = tt_n * 1024 + t;
        v4f nxt[4];
        if (have_next) {
            #pragma unroll
            for (int k = 0; k < 4; ++k) nxt[k] = xv[base_n + 256 * k];
        }

        // ---- neighbor chunks via intra-wave shuffles (rows never straddle a wave) ----
        float up_y[4], up_z[4], up_w[4], dn_x[4], dn_y[4], dn_z[4];
        #pragma unroll
        for (int k = 0; k < 4; ++k) {
            up_y[k] = __shfl_up(cur[k].y, 1);
            up_z[k] = __shfl_up(cur[k].z, 1);
            up_w[k] = __shfl_up(cur[k].w, 1);
            dn_x[k] = __shfl_down(cur[k].x, 1);
            dn_y[k] = __shfl_down(cur[k].y, 1);
            dn_z[k] = __shfl_down(cur[k].z, 1);
        }

        v4f r[4];
        if (j == 0) {
            #pragma unroll
            for (int k = 0; k < 4; ++k) {
                r[k].x = s[70] + cur[k].x * s[0];
                r[k].y = s[71] + cur[k].y * s[1] + cur[k].z * s[2]  + cur[k].w * s[3]  + dn_x[k] * s[4];
                r[k].z = s[72] + cur[k].y * s[5] + cur[k].z * s[6]  + cur[k].w * s[7]  + dn_x[k] * s[8];
                r[k].w = s[73] + cur[k].y * s[9] + cur[k].z * s[10] + cur[k].w * s[11] + dn_x[k] * s[12];
            }
        } else if (j == 1) {
            #pragma unroll
            for (int k = 0; k < 4; ++k) {
                r[k].x = s[74] + up_y[k] * s[13] + up_z[k] * s[14] + up_w[k] * s[15] + cur[k].x * s[16];
                r[k].y = s[75] + cur[k].y * s[17] + cur[k].z * s[18] + cur[k].w * s[19]
                               + dn_x[k] * s[20] + dn_y[k] * s[21] + dn_z[k] * s[22];
                r[k].z = s[76] + cur[k].y * s[23] + cur[k].z * s[24] + cur[k].w * s[25]
                               + dn_x[k] * s[26] + dn_y[k] * s[27] + dn_z[k] * s[28];
                r[k].w = s[77] + cur[k].y * s[29] + cur[k].z * s[30] + cur[k].w * s[31]
                               + dn_x[k] * s[32] + dn_y[k] * s[33] + dn_z[k] * s[34];
            }
        } else if (j == 2) {
            #pragma unroll
            for (int k = 0; k < 4; ++k) {
                r[k].x = s[78] + up_y[k] * s[35] + up_z[k] * s[36] + up_w[k] * s[37]
                               + cur[k].x * s[38] + cur[k].y * s[39] + cur[k].z * s[40];
                r[k].y = s[79] + up_y[k] * s[41] + up_z[k] * s[42] + up_w[k] * s[43]
                               + cur[k].x * s[44] + cur[k].y * s[45] + cur[k].z * s[46];
                r[k].z = s[80] + up_y[k] * s[47] + up_z[k] * s[48] + up_w[k] * s[49]
                               + cur[k].x * s[50] + cur[k].y * s[51] + cur[k].z * s[52];
                r[k].w = s[81] + cur[k].w * s[53] + dn_x[k] * s[54] + dn_y[k] * s[55] + dn_z[k] * s[56];
            }
        } else {
            #pragma unroll
            for (int k = 0; k < 4; ++k) {
                r[k].x = s[82] + up_w[k] * s[57] + cur[k].x * s[58] + cur[k].y * s[59] + cur[k].z * s[60];
                r[k].y = s[83] + up_w[k] * s[61] + cur[k].x * s[62] + cur[k].y * s[63] + cur[k].z * s[64];
                r[k].z = s[84] + up_w[k] * s[65] + cur[k].x * s[66] + cur[k].y * s[67] + cur[k].z * s[68];
                r[k].w = s[85] + cur[k].w * s[69];
            }
        }

        #pragma unroll
        for (int k = 0; k < 4; ++k)
            __builtin_nontemporal_store(r[k], ov + base + 256 * k);

        if (!have_next) break;
        #pragma unroll
        for (int k = 0; k < 4; ++k) cur[k] = nxt[k];
        tt = tt_n;
        base = base_n;
    }
}

extern "C" void kernel_launch(void* const* d_in, const int* in_sizes, int n_in,
                              void* d_out, int out_size, void* d_ws, size_t ws_size,
                              hipStream_t stream) {
    const float* x  = (const float*)d_in[0];
    const float* w0 = (const float*)d_in[1];
    const float* b0 = (const float*)d_in[2];
    const float* w1 = (const float*)d_in[3];
    const float* b1 = (const float*)d_in[4];
    const float* w2 = (const float*)d_in[5];
    const float* b2 = (const float*)d_in[6];
    const float* w3 = (const float*)d_in[7];
    const float* b3 = (const float*)d_in[8];
    const float* w4 = (const float*)d_in[9];
    const float* b4 = (const float*)d_in[10];
    float* out = (float*)d_out;

    int n4 = in_sizes[0] / 4;          // 8,388,608 float4 chunks
    int n_tiles = n4 / 1024;           // 8192 tiles of 1024 chunks
    int block = 256;
    int grid = 1024;                   // persistent: ~4 blocks/CU, 8 tiles each

    GradeWiseLinear_kernel<<<grid, block, 0, stream>>>(
        x, w0, b0, w1, b1, w2, b2, w3, b3, w4, b4, out, n_tiles);
}